// Round 3
// baseline (245.510 us; speedup 1.0000x reference)
//
#include <hip/hip_runtime.h>
#include <math.h>

// Problem constants (from reference setup_inputs)
#define B   16
#define NH  1024
#define NO  2048
#define DQ  24

#define ALPHA_FOCAL 0.25f
#define MARGIN_PEN  0.005f
#define RADIUS_REP  0.015f
#define R2REP       (RADIUS_REP * RADIUS_REP)

// ws layout (floats):
//  [0..5]  scalar accumulators:
//    0: hand chamfer dir1   1: hand chamfer dir2
//    2: obj chamfer dir1 (weighted)   3: obj chamfer dir2 (weighted)
//    4: repulsion raw (incl. diagonal, weighted)   5: penetration (weighted)
//  [16 .. 16+65536)        obj-cd dir1 partial d2: [qchunk(2)][b(16)][n(2048)]
//  [16+65536 .. 16+131072) obj-cd dir2 partial d2
#define WS_SCAL   16
#define WS_SEG    65536
#define WS_NEEDED ((WS_SCAL + 2 * WS_SEG) * sizeof(float))

__device__ inline float block_reduce_sum(float v, float* red) {
    #pragma unroll
    for (int off = 32; off > 0; off >>= 1) v += __shfl_down(v, off, 64);
    int lane = threadIdx.x & 63;
    int wid  = threadIdx.x >> 6;
    if (lane == 0) red[wid] = v;
    __syncthreads();
    float s = 0.f;
    if (threadIdx.x == 0) s = red[0] + red[1] + red[2] + red[3];
    __syncthreads();
    return s;   // valid in thread 0 only
}

// Each block: 256 threads, 4 P-points per thread (1024 P rows), inner loop over
// NQ staged Q points in LDS (float4 {x,y,z,|q|^2}).
// split=1: 256 uniform blocks (NQ=1024 everywhere; obj-chamfer Q split in 2
//          chunks -> partial d2 mins written to ws arrays).
// split=0: 160 blocks (obj segs use full NQ=2048, complete in-block).
__global__ __launch_bounds__(256) void pairwise_kernel(
    const float* __restrict__ pred_hand, const float* __restrict__ pred_obj,
    const float* __restrict__ gt_hand,   const float* __restrict__ gt_obj,
    const float* __restrict__ has_contact, float* __restrict__ ws, int split)
{
    __shared__ float4 q[2048];      // 32 KiB (split mode uses first 1024)
    __shared__ float  red[4];

    const int tid = threadIdx.x;
    const int blk = blockIdx.x;

    const float* Pb; const float* Qb;
    int mode, slot, b, NQ;
    float* pout = nullptr;

    if (split) {
        if (blk < 32) {                 // hand chamfer (complete)
            b = blk & 15;
            if (blk < 16) { Pb = pred_hand + b*NH*3; Qb = gt_hand   + b*NH*3; slot = 0; }
            else          { Pb = gt_hand   + b*NH*3; Qb = pred_hand + b*NH*3; slot = 1; }
            mode = 0; NQ = 1024;
        } else if (blk < 160) {         // obj chamfer (partial min over Q-chunk)
            int local = blk - 32;       // 0..127
            int s  = local >> 6;        // 0: dir1, 1: dir2
            int l2 = local & 63;
            b = l2 >> 2;
            int pchunk = (l2 >> 1) & 1, qchunk = l2 & 1;
            const float* po = pred_obj + b*NO*3;
            const float* go = gt_obj   + b*NO*3;
            if (s == 0) { Pb = po + pchunk*1024*3; Qb = go + qchunk*1024*3; }
            else        { Pb = go + pchunk*1024*3; Qb = po + qchunk*1024*3; }
            pout = ws + WS_SCAL + s*WS_SEG + (qchunk*16 + b)*2048 + pchunk*1024;
            mode = 3; slot = -1; NQ = 1024;
        } else if (blk < 224) {         // repulsion (diagonal included)
            int l2 = blk - 160;
            b = l2 >> 2;
            int pchunk = (l2 >> 1) & 1, qchunk = l2 & 1;
            const float* po = pred_obj + b*NO*3;
            Pb = po + pchunk*1024*3; Qb = po + qchunk*1024*3;
            mode = 1; slot = 4; NQ = 1024;
        } else {                        // penetration (complete)
            int l2 = blk - 224;
            b = l2 >> 1;
            int pchunk = l2 & 1;
            Pb = pred_obj + b*NO*3 + pchunk*1024*3;
            Qb = pred_hand + b*NH*3;
            mode = 2; slot = 5; NQ = 1024;
        }
    } else {
        if (blk < 32) {
            b = blk & 15;
            if (blk < 16) { Pb = pred_hand + b*NH*3; Qb = gt_hand   + b*NH*3; slot = 0; }
            else          { Pb = gt_hand   + b*NH*3; Qb = pred_hand + b*NH*3; slot = 1; }
            mode = 0; NQ = 1024;
        } else if (blk < 96) {
            int local = blk - 32;       // 0..63
            int s  = local >> 5;
            int l2 = local & 31;
            b = l2 >> 1;
            int pchunk = l2 & 1;
            const float* po = pred_obj + b*NO*3;
            const float* go = gt_obj   + b*NO*3;
            if (s == 0) { Pb = po + pchunk*1024*3; Qb = go; slot = 2; }
            else        { Pb = go + pchunk*1024*3; Qb = po; slot = 3; }
            mode = 0; NQ = 2048;
        } else if (blk < 128) {
            int l2 = blk - 96;
            b = l2 >> 1;
            int pchunk = l2 & 1;
            const float* po = pred_obj + b*NO*3;
            Pb = po + pchunk*1024*3; Qb = po;
            mode = 1; slot = 4; NQ = 2048;
        } else {
            int l2 = blk - 128;
            b = l2 >> 1;
            int pchunk = l2 & 1;
            Pb = pred_obj + b*NO*3 + pchunk*1024*3;
            Qb = pred_hand + b*NH*3;
            mode = 2; slot = 5; NQ = 1024;
        }
    }

    // Stage Q chunk into LDS as {x,y,z,|q|^2}
    for (int i = tid; i < NQ; i += 256) {
        float x = Qb[i*3+0], y = Qb[i*3+1], z = Qb[i*3+2];
        q[i] = make_float4(x, y, z, fmaf(x, x, fmaf(y, y, z*z)));
    }
    __syncthreads();

    // Load this thread's 4 P points
    float px[4], py[4], pz[4], pn[4];
    #pragma unroll
    for (int k = 0; k < 4; ++k) {
        int n = tid + k*256;
        px[k] = Pb[n*3+0]; py[k] = Pb[n*3+1]; pz[k] = Pb[n*3+2];
        pn[k] = fmaf(px[k], px[k], fmaf(py[k], py[k], pz[k]*pz[k]));
    }

    float val;
    if (mode == 1) {
        // repulsion: sum relu(R - d) over all pairs (diagonal kept; subtracted
        // in finalize — d2 on the diagonal is bit-exact 0 by construction)
        float s = 0.f;
        #pragma unroll 4
        for (int j = 0; j < NQ; ++j) {
            float4 Q4 = q[j];
            #pragma unroll
            for (int k = 0; k < 4; ++k) {
                float t  = fmaf(px[k], Q4.x, fmaf(py[k], Q4.y, pz[k]*Q4.z));
                float d2 = fmaf(-2.f, t, pn[k] + Q4.w);
                if (d2 < R2REP) s += RADIUS_REP - sqrtf(fmaxf(d2, 1e-12f));
            }
        }
        val = s;
    } else {
        float m[4] = {1e30f, 1e30f, 1e30f, 1e30f};
        #pragma unroll 4
        for (int j = 0; j < NQ; ++j) {
            float4 Q4 = q[j];
            #pragma unroll
            for (int k = 0; k < 4; ++k) {
                float t  = fmaf(px[k], Q4.x, fmaf(py[k], Q4.y, pz[k]*Q4.z));
                float d2 = fmaf(-2.f, t, pn[k] + Q4.w);
                m[k] = fminf(m[k], d2);
            }
        }
        if (mode == 3) {                // partial: store raw d2 mins
            #pragma unroll
            for (int k = 0; k < 4; ++k) pout[tid + k*256] = m[k];
            return;
        }
        float s = 0.f;
        #pragma unroll
        for (int k = 0; k < 4; ++k) {
            float d = sqrtf(fmaxf(m[k], 1e-12f));
            s += (mode == 2) ? fmaxf(MARGIN_PEN - d, 0.f) : d;
        }
        val = s;
    }

    float bs = block_reduce_sum(val, red);
    if (tid == 0) {
        float w = (slot >= 2) ? has_contact[b] : 1.f;
        atomicAdd(&ws[slot], bs * w);
    }
}

// Combine the two Q-chunk partial mins for obj chamfer (split mode only).
__global__ __launch_bounds__(256) void combine_kernel(
    const float* __restrict__ has_contact, float* __restrict__ ws)
{
    __shared__ float red[4];
    int s = blockIdx.x >> 4;            // 0: dir1, 1: dir2
    int b = blockIdx.x & 15;
    const float* p0 = ws + WS_SCAL + s*WS_SEG + (0*16 + b)*2048;
    const float* p1 = ws + WS_SCAL + s*WS_SEG + (1*16 + b)*2048;
    float sum = 0.f;
    for (int n = threadIdx.x; n < 2048; n += 256) {
        float m = fminf(p0[n], p1[n]);
        sum += sqrtf(fmaxf(m, 1e-12f));
    }
    float bs = block_reduce_sum(sum, red);
    if (threadIdx.x == 0) atomicAdd(&ws[2 + s], bs * has_contact[b]);
}

__global__ __launch_bounds__(256) void finalize_kernel(
    const float* __restrict__ pred_pose, const float* __restrict__ pred_qpos,
    const float* __restrict__ logits,
    const float* __restrict__ gt_pose,   const float* __restrict__ gt_qpos,
    const float* __restrict__ gt_contact, const float* __restrict__ has_contact,
    const float* __restrict__ ws, float* __restrict__ out)
{
    __shared__ float red[4];
    int tid = threadIdx.x;

    // focal (contact) loss sum over B*NH
    float fsum = 0.f;
    for (int i = tid; i < B*NH; i += 256) {
        float l = logits[i];
        float y = gt_contact[i];
        float bce = fmaxf(l, 0.f) - l*y + log1pf(expf(-fabsf(l)));
        float pt  = expf(-bce);
        float om  = 1.f - pt;
        fsum += ALPHA_FOCAL * om * om * bce;
    }

    // qpos MSE sum over B*DQ
    float qsum = 0.f;
    for (int i = tid; i < B*DQ; i += 256) {
        float d = pred_qpos[i] - gt_qpos[i];
        qsum += d*d;
    }

    // pose loss (per batch, weighted) + valid sum
    float psum = 0.f, vsum = 0.f;
    if (tid < B) {
        const float* pp = pred_pose + tid*7;
        const float* gp = gt_pose   + tid*7;
        float lt = (fabsf(pp[0]-gp[0]) + fabsf(pp[1]-gp[1]) + fabsf(pp[2]-gp[2])) * (1.f/3.f);
        float npn = sqrtf(pp[3]*pp[3] + pp[4]*pp[4] + pp[5]*pp[5] + pp[6]*pp[6]);
        float ngn = sqrtf(gp[3]*gp[3] + gp[4]*gp[4] + gp[5]*gp[5] + gp[6]*gp[6]);
        float dot = (pp[3]*gp[3] + pp[4]*gp[4] + pp[5]*gp[5] + pp[6]*gp[6]) / (npn * ngn);
        float lr = 1.f - fabsf(dot);
        psum = (lt + 0.1f*lr) * has_contact[tid];
        vsum = has_contact[tid];
    }

    float fT = block_reduce_sum(fsum, red);
    float qT = block_reduce_sum(qsum, red);
    float pT = block_reduce_sum(psum, red);
    float vT = block_reduce_sum(vsum, red);

    if (tid == 0) {
        float valid = vT + 1e-6f;
        // repulsion diagonal adjustment: each of the NO diagonal pairs
        // contributed exactly RADIUS_REP - sqrt(1e-12), weighted by hc[b]
        float diag  = RADIUS_REP - sqrtf(1e-12f);
        float rep   = ws[4] - vT * (float)NO * diag;

        float loss_cd_hand = (ws[0] + ws[1]) * (1.f / (B * NH));
        float loss_cd_obj  = (ws[2] + ws[3]) / ((float)NO * valid);
        float loss_rep     =  rep / ((float)NO * (float)NO * valid);
        float loss_pen     =  ws[5] / ((float)NO * valid);
        float loss_pose    =  pT / valid;
        float loss_qpos    =  qT * (1.f / (B * DQ));
        float loss_contact =  fT * (1.f / (B * NH));
        float total = 5.0f*loss_cd_hand + 5.0f*loss_cd_obj + 2.0f*loss_pose
                    + 1.0f*loss_qpos + 2.0f*loss_contact
                    + 0.5f*loss_rep + 0.5f*loss_pen;
        out[0] = total;
    }
}

extern "C" void kernel_launch(void* const* d_in, const int* in_sizes, int n_in,
                              void* d_out, int out_size, void* d_ws, size_t ws_size,
                              hipStream_t stream) {
    const float* pred_hand   = (const float*)d_in[0];
    const float* pred_obj    = (const float*)d_in[1];
    const float* pred_pose   = (const float*)d_in[2];
    const float* pred_qpos   = (const float*)d_in[3];
    const float* logits      = (const float*)d_in[4];
    const float* gt_hand     = (const float*)d_in[5];
    const float* gt_obj      = (const float*)d_in[6];
    const float* gt_pose     = (const float*)d_in[7];
    const float* gt_qpos     = (const float*)d_in[8];
    const float* gt_contact  = (const float*)d_in[9];
    const float* has_contact = (const float*)d_in[10];

    float* ws = (float*)d_ws;
    const int split = (ws_size >= WS_NEEDED) ? 1 : 0;

    hipMemsetAsync(ws, 0, 8 * sizeof(float), stream);

    pairwise_kernel<<<split ? 256 : 160, 256, 0, stream>>>(
        pred_hand, pred_obj, gt_hand, gt_obj, has_contact, ws, split);
    if (split)
        combine_kernel<<<32, 256, 0, stream>>>(has_contact, ws);
    finalize_kernel<<<1, 256, 0, stream>>>(pred_pose, pred_qpos, logits,
                                           gt_pose, gt_qpos, gt_contact, has_contact,
                                           ws, (float*)d_out);
}

// Round 4
// 116.079 us; speedup vs baseline: 2.1150x; 2.1150x over previous
//
#include <hip/hip_runtime.h>
#include <math.h>

// Problem constants (from reference setup_inputs)
#define B   16
#define NH  1024
#define NO  2048
#define DQ  24

#define ALPHA_FOCAL 0.25f
#define MARGIN_PEN  0.005f
#define RADIUS_REP  0.015f
#define R2REP       (RADIUS_REP * RADIUS_REP)

// ws layout:
//   float [0..8)   scalar accumulators:
//     0: hand cd dir1   1: hand cd dir2
//     2: obj  cd dir1 (weighted)   3: obj cd dir2 (weighted)
//     4: repulsion raw (diag included, weighted)   5: penetration (weighted)
//   uint  [16..16+131072)  per-row min d2 (clamped >=1e-12, float bits):
//     hand d1 [0,16384)  hand d2 [16384,32768)
//     obj  d1 [32768,65536)  obj d2 [65536,98304)  pen [98304,131072)
#define WS_SCAL    16
#define ROWS_TOTAL 131072

__device__ inline float block_reduce_sum(float v, float* red) {
    #pragma unroll
    for (int off = 32; off > 0; off >>= 1) v += __shfl_down(v, off, 64);
    int lane = threadIdx.x & 63;
    int wid  = threadIdx.x >> 6;
    if (lane == 0) red[wid] = v;
    __syncthreads();
    float s = 0.f;
    if (threadIdx.x == 0) s = red[0] + red[1] + red[2] + red[3];
    __syncthreads();
    return s;   // valid in thread 0 only
}

// 1024 uniform blocks, 256 threads, 4 P-rows/thread (1024 rows) x 256 Q cols.
//  [  0, 128): hand chamfer   dir(1b) x b(16) x jc(4)
//  [128, 640): obj  chamfer   dir(1b) x b(16) x pc(2) x jc(8)
//  [640, 896): repulsion      b(16) x pc(2) x jc(8)
//  [896,1024): penetration    b(16) x pc(2) x jc(4)
__global__ __launch_bounds__(256) void pairwise_kernel(
    const float* __restrict__ pred_hand, const float* __restrict__ pred_obj,
    const float* __restrict__ gt_hand,   const float* __restrict__ gt_obj,
    const float* __restrict__ has_contact, float* __restrict__ ws)
{
    __shared__ float4 q[256];     // 4 KiB
    __shared__ float  red[4];

    const int tid = threadIdx.x;
    const int blk = blockIdx.x;
    unsigned* rowmin = (unsigned*)(ws + WS_SCAL);

    const float* Pb; const float* Qb;
    int b, rowbase = 0, rep = 0;

    if (blk < 128) {                        // hand chamfer
        int dir = blk >> 6, l = blk & 63;
        b = l >> 2; int jc = l & 3;
        Pb = (dir ? gt_hand : pred_hand) + b*NH*3;
        Qb = (dir ? pred_hand : gt_hand) + b*NH*3 + jc*256*3;
        rowbase = dir*16384 + b*1024;
    } else if (blk < 640) {                 // obj chamfer
        int idx = blk - 128;
        int dir = idx >> 8, l = idx & 255;
        b = l >> 4; int pc = (l >> 3) & 1, jc = l & 7;
        Pb = (dir ? gt_obj : pred_obj) + b*NO*3 + pc*1024*3;
        Qb = (dir ? pred_obj : gt_obj) + b*NO*3 + jc*256*3;
        rowbase = 32768 + dir*32768 + b*2048 + pc*1024;
    } else if (blk < 896) {                 // repulsion
        int idx = blk - 640;
        b = idx >> 4; int pc = (idx >> 3) & 1, jc = idx & 7;
        Pb = pred_obj + b*NO*3 + pc*1024*3;
        Qb = pred_obj + b*NO*3 + jc*256*3;
        rep = 1;
    } else {                                // penetration
        int idx = blk - 896;
        b = idx >> 3; int pc = (idx >> 2) & 1, jc = idx & 3;
        Pb = pred_obj  + b*NO*3 + pc*1024*3;
        Qb = pred_hand + b*NH*3 + jc*256*3;
        rowbase = 98304 + b*2048 + pc*1024;
    }

    // Stage 256 Q points into LDS as {x,y,z,|q|^2}
    {
        float x = Qb[tid*3+0], y = Qb[tid*3+1], z = Qb[tid*3+2];
        q[tid] = make_float4(x, y, z, fmaf(x, x, fmaf(y, y, z*z)));
    }
    __syncthreads();

    // This thread's 4 P points
    float px[4], py[4], pz[4], pn[4];
    #pragma unroll
    for (int k = 0; k < 4; ++k) {
        int n = tid + k*256;
        px[k] = Pb[n*3+0]; py[k] = Pb[n*3+1]; pz[k] = Pb[n*3+2];
        pn[k] = fmaf(px[k], px[k], fmaf(py[k], py[k], pz[k]*pz[k]));
    }

    if (rep) {
        // sum relu(R - d) over all pairs (diagonal kept; d2 there is bit-exact
        // 0 by construction -> contributes R - 1e-6, subtracted in finalize)
        float s = 0.f;
        #pragma unroll 8
        for (int j = 0; j < 256; ++j) {
            float4 Q4 = q[j];
            #pragma unroll
            for (int k = 0; k < 4; ++k) {
                float t  = fmaf(px[k], Q4.x, fmaf(py[k], Q4.y, pz[k]*Q4.z));
                float d2 = fmaf(-2.f, t, pn[k] + Q4.w);
                if (d2 < R2REP) s += RADIUS_REP - sqrtf(fmaxf(d2, 1e-12f));
            }
        }
        float bs = block_reduce_sum(s, red);
        if (tid == 0) atomicAdd(&ws[4], bs * has_contact[b]);
    } else {
        float m[4] = {1e30f, 1e30f, 1e30f, 1e30f};
        #pragma unroll 8
        for (int j = 0; j < 256; ++j) {
            float4 Q4 = q[j];
            #pragma unroll
            for (int k = 0; k < 4; ++k) {
                float t  = fmaf(px[k], Q4.x, fmaf(py[k], Q4.y, pz[k]*Q4.z));
                float d2 = fmaf(-2.f, t, pn[k] + Q4.w);
                m[k] = fminf(m[k], d2);
            }
        }
        // merge partial mins across Q-chunks (clamped positive -> uint order
        // == float order)
        #pragma unroll
        for (int k = 0; k < 4; ++k) {
            unsigned bits = __float_as_uint(fmaxf(m[k], 1e-12f));
            atomicMin(&rowmin[rowbase + tid + k*256], bits);
        }
    }
}

// 80 blocks: reduce per-row mins into weighted scalar sums.
//  [0,32): hand (dir x b)   [32,64): obj (dir x b)   [64,80): pen (b)
__global__ __launch_bounds__(256) void combine_kernel(
    const float* __restrict__ has_contact, float* __restrict__ ws)
{
    __shared__ float red[4];
    const unsigned* rowmin = (const unsigned*)(ws + WS_SCAL);
    int blk = blockIdx.x;

    int slot, rows, base, pen = 0;
    float w = 1.f;
    if (blk < 32) {
        int dir = blk >> 4, b = blk & 15;
        slot = dir; rows = 1024; base = dir*16384 + b*1024;
    } else if (blk < 64) {
        int idx = blk - 32; int dir = idx >> 4, b = idx & 15;
        slot = 2 + dir; rows = 2048; base = 32768 + dir*32768 + b*2048;
        w = has_contact[b];
    } else {
        int b = blk - 64;
        slot = 5; rows = 2048; base = 98304 + b*2048;
        w = has_contact[b]; pen = 1;
    }

    float s = 0.f;
    for (int n = threadIdx.x; n < rows; n += 256) {
        float d = sqrtf(__uint_as_float(rowmin[base + n]));
        s += pen ? fmaxf(MARGIN_PEN - d, 0.f) : d;
    }
    float bs = block_reduce_sum(s, red);
    if (threadIdx.x == 0) atomicAdd(&ws[slot], bs * w);
}

__global__ __launch_bounds__(256) void finalize_kernel(
    const float* __restrict__ pred_pose, const float* __restrict__ pred_qpos,
    const float* __restrict__ logits,
    const float* __restrict__ gt_pose,   const float* __restrict__ gt_qpos,
    const float* __restrict__ gt_contact, const float* __restrict__ has_contact,
    const float* __restrict__ ws, float* __restrict__ out)
{
    __shared__ float red[4];
    int tid = threadIdx.x;

    // focal (contact) loss sum over B*NH
    float fsum = 0.f;
    for (int i = tid; i < B*NH; i += 256) {
        float l = logits[i];
        float y = gt_contact[i];
        float bce = fmaxf(l, 0.f) - l*y + log1pf(expf(-fabsf(l)));
        float pt  = expf(-bce);
        float om  = 1.f - pt;
        fsum += ALPHA_FOCAL * om * om * bce;
    }

    // qpos MSE sum over B*DQ
    float qsum = 0.f;
    for (int i = tid; i < B*DQ; i += 256) {
        float d = pred_qpos[i] - gt_qpos[i];
        qsum += d*d;
    }

    // pose loss (per batch, weighted) + valid sum
    float psum = 0.f, vsum = 0.f;
    if (tid < B) {
        const float* pp = pred_pose + tid*7;
        const float* gp = gt_pose   + tid*7;
        float lt = (fabsf(pp[0]-gp[0]) + fabsf(pp[1]-gp[1]) + fabsf(pp[2]-gp[2])) * (1.f/3.f);
        float npn = sqrtf(pp[3]*pp[3] + pp[4]*pp[4] + pp[5]*pp[5] + pp[6]*pp[6]);
        float ngn = sqrtf(gp[3]*gp[3] + gp[4]*gp[4] + gp[5]*gp[5] + gp[6]*gp[6]);
        float dot = (pp[3]*gp[3] + pp[4]*gp[4] + pp[5]*gp[5] + pp[6]*gp[6]) / (npn * ngn);
        float lr = 1.f - fabsf(dot);
        psum = (lt + 0.1f*lr) * has_contact[tid];
        vsum = has_contact[tid];
    }

    float fT = block_reduce_sum(fsum, red);
    float qT = block_reduce_sum(qsum, red);
    float pT = block_reduce_sum(psum, red);
    float vT = block_reduce_sum(vsum, red);

    if (tid == 0) {
        float valid = vT + 1e-6f;
        // repulsion diagonal adjustment: each diagonal pair contributed
        // exactly RADIUS_REP - sqrt(1e-12), weighted by hc[b]
        float diag  = RADIUS_REP - sqrtf(1e-12f);
        float rep   = ws[4] - vT * (float)NO * diag;

        float loss_cd_hand = (ws[0] + ws[1]) * (1.f / (B * NH));
        float loss_cd_obj  = (ws[2] + ws[3]) / ((float)NO * valid);
        float loss_rep     =  rep / ((float)NO * (float)NO * valid);
        float loss_pen     =  ws[5] / ((float)NO * valid);
        float loss_pose    =  pT / valid;
        float loss_qpos    =  qT * (1.f / (B * DQ));
        float loss_contact =  fT * (1.f / (B * NH));
        float total = 5.0f*loss_cd_hand + 5.0f*loss_cd_obj + 2.0f*loss_pose
                    + 1.0f*loss_qpos + 2.0f*loss_contact
                    + 0.5f*loss_rep + 0.5f*loss_pen;
        out[0] = total;
    }
}

extern "C" void kernel_launch(void* const* d_in, const int* in_sizes, int n_in,
                              void* d_out, int out_size, void* d_ws, size_t ws_size,
                              hipStream_t stream) {
    const float* pred_hand   = (const float*)d_in[0];
    const float* pred_obj    = (const float*)d_in[1];
    const float* pred_pose   = (const float*)d_in[2];
    const float* pred_qpos   = (const float*)d_in[3];
    const float* logits      = (const float*)d_in[4];
    const float* gt_hand     = (const float*)d_in[5];
    const float* gt_obj      = (const float*)d_in[6];
    const float* gt_pose     = (const float*)d_in[7];
    const float* gt_qpos     = (const float*)d_in[8];
    const float* gt_contact  = (const float*)d_in[9];
    const float* has_contact = (const float*)d_in[10];

    float* ws = (float*)d_ws;

    // scalars <- 0 ; row-min region <- 0xFFFFFFFF (uint max)
    hipMemsetAsync(ws, 0, WS_SCAL * sizeof(float), stream);
    hipMemsetAsync(ws + WS_SCAL, 0xFF, ROWS_TOTAL * sizeof(unsigned), stream);

    pairwise_kernel<<<1024, 256, 0, stream>>>(pred_hand, pred_obj, gt_hand, gt_obj,
                                              has_contact, ws);
    combine_kernel<<<80, 256, 0, stream>>>(has_contact, ws);
    finalize_kernel<<<1, 256, 0, stream>>>(pred_pose, pred_qpos, logits,
                                           gt_pose, gt_qpos, gt_contact, has_contact,
                                           ws, (float*)d_out);
}

// Round 5
// 94.976 us; speedup vs baseline: 2.5850x; 1.2222x over previous
//
#include <hip/hip_runtime.h>
#include <math.h>

// Problem constants (from reference setup_inputs)
#define B   16
#define NH  1024
#define NO  2048
#define DQ  24

#define ALPHA_FOCAL 0.25f
#define MARGIN_PEN  0.005f
#define RADIUS_REP  0.015f

// ws layout:
//   float [0..16)  scalar accumulators:
//     0: hand cd dir1   1: hand cd dir2
//     2: obj  cd dir1 (weighted)   3: obj cd dir2 (weighted)
//     4: repulsion raw (diag included, weighted)   5: penetration (weighted)
//     6: focal sum   7: qpos sq-sum   8: pose weighted sum   9: valid sum
//   uint  [16..16+131072)  per-row min d2 (clamped >=1e-12, float bits):
//     hand d1 [0,16384)  hand d2 [16384,32768)
//     obj  d1 [32768,65536)  obj d2 [65536,98304)  pen [98304,131072)
#define WS_SCAL    16
#define ROWS_TOTAL 131072
#define JC         128     // Q-chunk columns per block

__device__ inline float block_reduce_sum(float v, float* red) {
    #pragma unroll
    for (int off = 32; off > 0; off >>= 1) v += __shfl_down(v, off, 64);
    int lane = threadIdx.x & 63;
    int wid  = threadIdx.x >> 6;
    if (lane == 0) red[wid] = v;
    __syncthreads();
    float s = 0.f;
    if (threadIdx.x == 0) s = red[0] + red[1] + red[2] + red[3];
    __syncthreads();
    return s;   // valid in thread 0 only
}

// 2048 uniform blocks, 256 threads, 4 P-rows/thread (1024 rows) x 128 Q cols.
//  [   0, 256): hand chamfer   dir(2) x b(16) x jc(8)
//  [ 256,1280): obj  chamfer   dir(2) x b(16) x pc(2) x jc(16)
//  [1280,1792): repulsion      b(16) x pc(2) x jc(16)
//  [1792,2048): penetration    b(16) x pc(2) x jc(8)
__global__ __launch_bounds__(256) void pairwise_kernel(
    const float* __restrict__ pred_hand, const float* __restrict__ pred_obj,
    const float* __restrict__ gt_hand,   const float* __restrict__ gt_obj,
    const float* __restrict__ has_contact, float* __restrict__ ws)
{
    __shared__ float4 q[JC];      // 2 KiB; {-2x,-2y,-2z,|q|^2}
    __shared__ float  red[4];

    const int tid = threadIdx.x;
    const int blk = blockIdx.x;
    unsigned* rowmin = (unsigned*)(ws + WS_SCAL);

    const float* Pb; const float* Qb;
    int b, rowbase = 0, rep = 0;

    if (blk < 256) {                        // hand chamfer
        int dir = blk >> 7, l = blk & 127;
        b = l >> 3; int jc = l & 7;
        Pb = (dir ? gt_hand : pred_hand) + b*NH*3;
        Qb = (dir ? pred_hand : gt_hand) + b*NH*3 + jc*JC*3;
        rowbase = dir*16384 + b*1024;
    } else if (blk < 1280) {                // obj chamfer
        int idx = blk - 256;
        int dir = idx >> 9, l = idx & 511;
        b = l >> 5; int pc = (l >> 4) & 1, jc = l & 15;
        Pb = (dir ? gt_obj : pred_obj) + b*NO*3 + pc*1024*3;
        Qb = (dir ? pred_obj : gt_obj) + b*NO*3 + jc*JC*3;
        rowbase = 32768 + dir*32768 + b*2048 + pc*1024;
    } else if (blk < 1792) {                // repulsion
        int idx = blk - 1280;
        b = idx >> 5; int pc = (idx >> 4) & 1, jc = idx & 15;
        Pb = pred_obj + b*NO*3 + pc*1024*3;
        Qb = pred_obj + b*NO*3 + jc*JC*3;
        rep = 1;
    } else {                                // penetration
        int idx = blk - 1792;
        b = idx >> 4; int pc = (idx >> 3) & 1, jc = idx & 7;
        Pb = pred_obj  + b*NO*3 + pc*1024*3;
        Qb = pred_hand + b*NH*3 + jc*JC*3;
        rowbase = 98304 + b*2048 + pc*1024;
    }

    // Stage Q chunk: {-2x, -2y, -2z, |q|^2}
    if (tid < JC) {
        float x = Qb[tid*3+0], y = Qb[tid*3+1], z = Qb[tid*3+2];
        q[tid] = make_float4(-2.f*x, -2.f*y, -2.f*z, fmaf(x, x, fmaf(y, y, z*z)));
    }
    __syncthreads();

    // This thread's 4 P points
    float px[4], py[4], pz[4], pn[4];
    #pragma unroll
    for (int k = 0; k < 4; ++k) {
        int n = tid + k*256;
        px[k] = Pb[n*3+0]; py[k] = Pb[n*3+1]; pz[k] = Pb[n*3+2];
        pn[k] = fmaf(px[k], px[k], fmaf(py[k], py[k], pz[k]*pz[k]));
    }

    if (rep) {
        // sum relu(R - d); d>=R contributes 0 automatically, so no compare.
        // Diagonal kept (d2 ~ 0 within ~1e-9); subtracted in finalize.
        float s = 0.f;
        #pragma unroll 4
        for (int j = 0; j < JC; ++j) {
            float4 Q4 = q[j];
            #pragma unroll
            for (int k = 0; k < 4; ++k) {
                float t  = fmaf(Q4.z, pz[k], Q4.w);
                t        = fmaf(Q4.y, py[k], t);
                t        = fmaf(Q4.x, px[k], t);
                float d2 = t + pn[k];
                float d  = sqrtf(fmaxf(d2, 1e-12f));
                s += fmaxf(RADIUS_REP - d, 0.f);
            }
        }
        float bs = block_reduce_sum(s, red);
        if (tid == 0) atomicAdd(&ws[4], bs * has_contact[b]);
    } else {
        // min over j of (qw - 2 p.q); pn added after the min (exact for min)
        float m[4] = {1e30f, 1e30f, 1e30f, 1e30f};
        #pragma unroll 8
        for (int j = 0; j < JC; ++j) {
            float4 Q4 = q[j];
            #pragma unroll
            for (int k = 0; k < 4; ++k) {
                float t = fmaf(Q4.z, pz[k], Q4.w);
                t       = fmaf(Q4.y, py[k], t);
                t       = fmaf(Q4.x, px[k], t);
                m[k] = fminf(m[k], t);
            }
        }
        #pragma unroll
        for (int k = 0; k < 4; ++k) {
            unsigned bits = __float_as_uint(fmaxf(m[k] + pn[k], 1e-12f));
            atomicMin(&rowmin[rowbase + tid + k*256], bits);
        }
    }
}

// 83 blocks: reduce per-row mins + small loss terms into ws scalars.
//  [0,32): hand (dir x b)  [32,64): obj (dir x b)  [64,80): pen (b)
//  80: focal   81: qpos   82: pose + valid
__global__ __launch_bounds__(256) void combine_kernel(
    const float* __restrict__ has_contact, const float* __restrict__ logits,
    const float* __restrict__ gt_contact,  const float* __restrict__ pred_qpos,
    const float* __restrict__ gt_qpos,     const float* __restrict__ pred_pose,
    const float* __restrict__ gt_pose,     float* __restrict__ ws)
{
    __shared__ float red[4];
    const unsigned* rowmin = (const unsigned*)(ws + WS_SCAL);
    int blk = blockIdx.x;
    int tid = threadIdx.x;

    if (blk < 80) {
        int slot, rows, base, pen = 0;
        float w = 1.f;
        if (blk < 32) {
            int dir = blk >> 4, b = blk & 15;
            slot = dir; rows = 1024; base = dir*16384 + b*1024;
        } else if (blk < 64) {
            int idx = blk - 32; int dir = idx >> 4, b = idx & 15;
            slot = 2 + dir; rows = 2048; base = 32768 + dir*32768 + b*2048;
            w = has_contact[b];
        } else {
            int b = blk - 64;
            slot = 5; rows = 2048; base = 98304 + b*2048;
            w = has_contact[b]; pen = 1;
        }
        float s = 0.f;
        for (int n = tid; n < rows; n += 256) {
            float d = sqrtf(__uint_as_float(rowmin[base + n]));
            s += pen ? fmaxf(MARGIN_PEN - d, 0.f) : d;
        }
        float bs = block_reduce_sum(s, red);
        if (tid == 0) atomicAdd(&ws[slot], bs * w);
    } else if (blk == 80) {
        float fsum = 0.f;
        for (int i = tid; i < B*NH; i += 256) {
            float l = logits[i];
            float y = gt_contact[i];
            float bce = fmaxf(l, 0.f) - l*y + log1pf(expf(-fabsf(l)));
            float pt  = expf(-bce);
            float om  = 1.f - pt;
            fsum += ALPHA_FOCAL * om * om * bce;
        }
        float fT = block_reduce_sum(fsum, red);
        if (tid == 0) atomicAdd(&ws[6], fT);
    } else if (blk == 81) {
        float qsum = 0.f;
        for (int i = tid; i < B*DQ; i += 256) {
            float d = pred_qpos[i] - gt_qpos[i];
            qsum += d*d;
        }
        float qT = block_reduce_sum(qsum, red);
        if (tid == 0) atomicAdd(&ws[7], qT);
    } else {
        float psum = 0.f, vsum = 0.f;
        if (tid < B) {
            const float* pp = pred_pose + tid*7;
            const float* gp = gt_pose   + tid*7;
            float lt = (fabsf(pp[0]-gp[0]) + fabsf(pp[1]-gp[1]) + fabsf(pp[2]-gp[2])) * (1.f/3.f);
            float npn = sqrtf(pp[3]*pp[3] + pp[4]*pp[4] + pp[5]*pp[5] + pp[6]*pp[6]);
            float ngn = sqrtf(gp[3]*gp[3] + gp[4]*gp[4] + gp[5]*gp[5] + gp[6]*gp[6]);
            float dot = (pp[3]*gp[3] + pp[4]*gp[4] + pp[5]*gp[5] + pp[6]*gp[6]) / (npn * ngn);
            float lr = 1.f - fabsf(dot);
            psum = (lt + 0.1f*lr) * has_contact[tid];
            vsum = has_contact[tid];
        }
        float pT = block_reduce_sum(psum, red);
        float vT = block_reduce_sum(vsum, red);
        if (tid == 0) { atomicAdd(&ws[8], pT); atomicAdd(&ws[9], vT); }
    }
}

__global__ void finalize_kernel(const float* __restrict__ ws, float* __restrict__ out)
{
    if (threadIdx.x == 0) {
        float vT    = ws[9];
        float valid = vT + 1e-6f;
        // repulsion diagonal adjustment (each diag pair ~ RADIUS_REP - 1e-6)
        float diag  = RADIUS_REP - sqrtf(1e-12f);
        float rep   = ws[4] - vT * (float)NO * diag;

        float loss_cd_hand = (ws[0] + ws[1]) * (1.f / (B * NH));
        float loss_cd_obj  = (ws[2] + ws[3]) / ((float)NO * valid);
        float loss_rep     =  rep / ((float)NO * (float)NO * valid);
        float loss_pen     =  ws[5] / ((float)NO * valid);
        float loss_pose    =  ws[8] / valid;
        float loss_qpos    =  ws[7] * (1.f / (B * DQ));
        float loss_contact =  ws[6] * (1.f / (B * NH));
        float total = 5.0f*loss_cd_hand + 5.0f*loss_cd_obj + 2.0f*loss_pose
                    + 1.0f*loss_qpos + 2.0f*loss_contact
                    + 0.5f*loss_rep + 0.5f*loss_pen;
        out[0] = total;
    }
}

extern "C" void kernel_launch(void* const* d_in, const int* in_sizes, int n_in,
                              void* d_out, int out_size, void* d_ws, size_t ws_size,
                              hipStream_t stream) {
    const float* pred_hand   = (const float*)d_in[0];
    const float* pred_obj    = (const float*)d_in[1];
    const float* pred_pose   = (const float*)d_in[2];
    const float* pred_qpos   = (const float*)d_in[3];
    const float* logits      = (const float*)d_in[4];
    const float* gt_hand     = (const float*)d_in[5];
    const float* gt_obj      = (const float*)d_in[6];
    const float* gt_pose     = (const float*)d_in[7];
    const float* gt_qpos     = (const float*)d_in[8];
    const float* gt_contact  = (const float*)d_in[9];
    const float* has_contact = (const float*)d_in[10];

    float* ws = (float*)d_ws;

    // scalars <- 0 ; row-min region <- 0xFFFFFFFF (uint max)
    hipMemsetAsync(ws, 0, WS_SCAL * sizeof(float), stream);
    hipMemsetAsync(ws + WS_SCAL, 0xFF, ROWS_TOTAL * sizeof(unsigned), stream);

    pairwise_kernel<<<2048, 256, 0, stream>>>(pred_hand, pred_obj, gt_hand, gt_obj,
                                              has_contact, ws);
    combine_kernel<<<83, 256, 0, stream>>>(has_contact, logits, gt_contact,
                                           pred_qpos, gt_qpos, pred_pose, gt_pose, ws);
    finalize_kernel<<<1, 64, 0, stream>>>(ws, (float*)d_out);
}

// Round 6
// 67.407 us; speedup vs baseline: 3.6422x; 1.4090x over previous
//
#include <hip/hip_runtime.h>
#include <math.h>

// Problem constants (from reference setup_inputs)
#define B   16
#define NH  1024
#define NO  2048
#define DQ  24

#define ALPHA_FOCAL 0.25f
#define MARGIN_PEN  0.005f
#define RADIUS_REP  0.015f
#define R2REP       (RADIUS_REP * RADIUS_REP)

// ws layout:
//   float [0..16) scalar slots:
//     0,1: hand cd dir1/dir2   2,3: obj cd dir1/dir2 (weighted)
//     4: repulsion shifted sum S=sum min(d,R) incl diag (weighted)
//     5: penetration (weighted)  6: focal  7: qpos  8: pose (weighted)
//     9: valid   15: combine ticket counter (uint)
//   uint [16..16+131072): per-row ~bits(min d2) via atomicMax (init 0):
//     hand d1 [0,16384) hand d2 [16384,32768)
//     obj d1 [32768,65536) obj d2 [65536,98304) pen [98304,131072)
#define WS_SCAL    16
#define ROWS_TOTAL 131072
#define JC         128     // Q columns per block

typedef float v2f __attribute__((ext_vector_type(2)));
typedef float v4f __attribute__((ext_vector_type(4)));

__device__ inline float wsqrt(float x) { return __builtin_amdgcn_sqrtf(x); }

__device__ inline float block_reduce_sum(float v, float* red) {
    #pragma unroll
    for (int off = 32; off > 0; off >>= 1) v += __shfl_down(v, off, 64);
    int lane = threadIdx.x & 63;
    int wid  = threadIdx.x >> 6;
    if (lane == 0) red[wid] = v;
    __syncthreads();
    float s = 0.f;
    if (threadIdx.x == 0) s = red[0] + red[1] + red[2] + red[3];
    __syncthreads();
    return s;   // valid in thread 0 only
}

// one packed step: 2 Q columns x 4 P rows. A={-2x0,-2x1,-2y0,-2y1} B={-2z0,-2z1,w0,w1}
__device__ inline void cham_step(v4f A, v4f Bv,
                                 const v2f px2[4], const v2f py2[4], const v2f pz2[4],
                                 v2f m2[4]) {
    v2f ax = A.lo, ay = A.hi, az = Bv.lo, aw = Bv.hi;
    #pragma unroll
    for (int k = 0; k < 4; ++k) {
        v2f t = __builtin_elementwise_fma(az, pz2[k], aw);
        t     = __builtin_elementwise_fma(ay, py2[k], t);
        t     = __builtin_elementwise_fma(ax, px2[k], t);
        m2[k] = __builtin_elementwise_min(m2[k], t);
    }
}

__device__ inline void rep_step(v4f A, v4f Bv,
                                const v2f px2[4], const v2f py2[4], const v2f pz2[4],
                                const v2f pn2[4], v2f* s2) {
    v2f ax = A.lo, ay = A.hi, az = Bv.lo, aw = Bv.hi;
    #pragma unroll
    for (int k = 0; k < 4; ++k) {
        v2f t = __builtin_elementwise_fma(az, pz2[k], aw);
        t     = __builtin_elementwise_fma(ay, py2[k], t);
        t     = __builtin_elementwise_fma(ax, px2[k], t);
        v2f d2 = t + pn2[k];
        v2f dd;
        dd.x = wsqrt(__builtin_amdgcn_fmed3f(d2.x, 1e-12f, R2REP));
        dd.y = wsqrt(__builtin_amdgcn_fmed3f(d2.y, 1e-12f, R2REP));
        *s2 += dd;   // sum of min(d, R): relu(R-d) = R - min(d,R), fixed in finalize
    }
}

// 2051 blocks:
//  [   0, 256): hand chamfer  dir(2) x b(16) x jc(8)
//  [ 256,1280): obj  chamfer  dir(2) x b(16) x pc(2) x jc(16)
//  [1280,1792): repulsion     b(16) x pc(2) x jc(16)
//  [1792,2048): penetration   b(16) x pc(2) x jc(8)
//  2048: focal  2049: qpos  2050: pose+valid
__global__ __launch_bounds__(256, 4) void pairwise_kernel(
    const float* __restrict__ pred_hand, const float* __restrict__ pred_obj,
    const float* __restrict__ gt_hand,   const float* __restrict__ gt_obj,
    const float* __restrict__ has_contact,
    const float* __restrict__ logits,    const float* __restrict__ gt_contact,
    const float* __restrict__ pred_qpos, const float* __restrict__ gt_qpos,
    const float* __restrict__ pred_pose, const float* __restrict__ gt_pose,
    float* __restrict__ ws)
{
    __shared__ v4f  qs[JC];   // 2 KiB: qs[2p]={-2x0,-2x1,-2y0,-2y1} qs[2p+1]={-2z0,-2z1,w0,w1}
    __shared__ float red[4];

    const int tid = threadIdx.x;
    const int blk = blockIdx.x;

    if (blk >= 2048) {        // small fused loss terms
        if (blk == 2048) {
            float fsum = 0.f;
            for (int i = tid; i < B*NH; i += 256) {
                float l = logits[i];
                float y = gt_contact[i];
                float bce = fmaxf(l, 0.f) - l*y + log1pf(expf(-fabsf(l)));
                float pt  = expf(-bce);
                float om  = 1.f - pt;
                fsum += ALPHA_FOCAL * om * om * bce;
            }
            float fT = block_reduce_sum(fsum, red);
            if (tid == 0) atomicAdd(&ws[6], fT);
        } else if (blk == 2049) {
            float qsum = 0.f;
            for (int i = tid; i < B*DQ; i += 256) {
                float d = pred_qpos[i] - gt_qpos[i];
                qsum += d*d;
            }
            float qT = block_reduce_sum(qsum, red);
            if (tid == 0) atomicAdd(&ws[7], qT);
        } else {
            float psum = 0.f, vsum = 0.f;
            if (tid < B) {
                const float* pp = pred_pose + tid*7;
                const float* gp = gt_pose   + tid*7;
                float lt = (fabsf(pp[0]-gp[0]) + fabsf(pp[1]-gp[1]) + fabsf(pp[2]-gp[2])) * (1.f/3.f);
                float npn = wsqrt(pp[3]*pp[3] + pp[4]*pp[4] + pp[5]*pp[5] + pp[6]*pp[6]);
                float ngn = wsqrt(gp[3]*gp[3] + gp[4]*gp[4] + gp[5]*gp[5] + gp[6]*gp[6]);
                float dot = (pp[3]*gp[3] + pp[4]*gp[4] + pp[5]*gp[5] + pp[6]*gp[6]) / (npn * ngn);
                float lr = 1.f - fabsf(dot);
                psum = (lt + 0.1f*lr) * has_contact[tid];
                vsum = has_contact[tid];
            }
            float pT = block_reduce_sum(psum, red);
            float vT = block_reduce_sum(vsum, red);
            if (tid == 0) { atomicAdd(&ws[8], pT); atomicAdd(&ws[9], vT); }
        }
        return;
    }

    unsigned* rowmin = (unsigned*)(ws + WS_SCAL);
    const float* Pb; const float* Qb;
    int b, rowbase = 0, rep = 0;

    if (blk < 256) {                        // hand chamfer
        int dir = blk >> 7, l = blk & 127;
        b = l >> 3; int jc = l & 7;
        Pb = (dir ? gt_hand : pred_hand) + b*NH*3;
        Qb = (dir ? pred_hand : gt_hand) + b*NH*3 + jc*JC*3;
        rowbase = dir*16384 + b*1024;
    } else if (blk < 1280) {                // obj chamfer
        int idx = blk - 256;
        int dir = idx >> 9, l = idx & 511;
        b = l >> 5; int pc = (l >> 4) & 1, jc = l & 15;
        Pb = (dir ? gt_obj : pred_obj) + b*NO*3 + pc*1024*3;
        Qb = (dir ? pred_obj : gt_obj) + b*NO*3 + jc*JC*3;
        rowbase = 32768 + dir*32768 + b*2048 + pc*1024;
    } else if (blk < 1792) {                // repulsion
        int idx = blk - 1280;
        b = idx >> 5; int pc = (idx >> 4) & 1, jc = idx & 15;
        Pb = pred_obj + b*NO*3 + pc*1024*3;
        Qb = pred_obj + b*NO*3 + jc*JC*3;
        rep = 1;
    } else {                                // penetration
        int idx = blk - 1792;
        b = idx >> 4; int pc = (idx >> 3) & 1, jc = idx & 7;
        Pb = pred_obj  + b*NO*3 + pc*1024*3;
        Qb = pred_hand + b*NH*3 + jc*JC*3;
        rowbase = 98304 + b*2048 + pc*1024;
    }

    // Stage JC columns, packed by pairs for v_pk math
    if (tid < JC) {
        float x = Qb[tid*3+0], y = Qb[tid*3+1], z = Qb[tid*3+2];
        float w = fmaf(x, x, fmaf(y, y, z*z));
        float* qf = (float*)qs;
        int p = tid >> 1, e = tid & 1;
        qf[p*8 + 0 + e] = -2.f*x;
        qf[p*8 + 2 + e] = -2.f*y;
        qf[p*8 + 4 + e] = -2.f*z;
        qf[p*8 + 6 + e] = w;
    }
    __syncthreads();

    // This thread's 4 P rows, broadcast into packed pairs
    float pn[4]; v2f px2[4], py2[4], pz2[4];
    #pragma unroll
    for (int k = 0; k < 4; ++k) {
        int n = tid + k*256;
        float x = Pb[n*3+0], y = Pb[n*3+1], z = Pb[n*3+2];
        px2[k] = (v2f){x, x}; py2[k] = (v2f){y, y}; pz2[k] = (v2f){z, z};
        pn[k]  = fmaf(x, x, fmaf(y, y, z*z));
    }

    if (!rep) {
        v2f m2[4] = {(v2f){1e30f,1e30f}, (v2f){1e30f,1e30f},
                     (v2f){1e30f,1e30f}, (v2f){1e30f,1e30f}};
        v4f A0=qs[0],B0=qs[1],A1=qs[2],B1=qs[3],A2=qs[4],B2=qs[5],A3=qs[6],B3=qs[7];
        for (int j2 = 0; j2 < 60; j2 += 4) {       // 4-deep register prefetch
            cham_step(A0,B0,px2,py2,pz2,m2); A0=qs[2*j2+ 8]; B0=qs[2*j2+ 9];
            cham_step(A1,B1,px2,py2,pz2,m2); A1=qs[2*j2+10]; B1=qs[2*j2+11];
            cham_step(A2,B2,px2,py2,pz2,m2); A2=qs[2*j2+12]; B2=qs[2*j2+13];
            cham_step(A3,B3,px2,py2,pz2,m2); A3=qs[2*j2+14]; B3=qs[2*j2+15];
        }
        cham_step(A0,B0,px2,py2,pz2,m2); cham_step(A1,B1,px2,py2,pz2,m2);
        cham_step(A2,B2,px2,py2,pz2,m2); cham_step(A3,B3,px2,py2,pz2,m2);

        #pragma unroll
        for (int k = 0; k < 4; ++k) {
            float mv = fminf(m2[k].x, m2[k].y) + pn[k];
            unsigned c = ~__float_as_uint(fmaxf(mv, 1e-12f));
            atomicMax(&rowmin[rowbase + tid + k*256], c);
        }
    } else {
        v2f pn2[4];
        #pragma unroll
        for (int k = 0; k < 4; ++k) pn2[k] = (v2f){pn[k], pn[k]};
        v2f s2 = (v2f){0.f, 0.f};
        v4f A0=qs[0],B0=qs[1],A1=qs[2],B1=qs[3],A2=qs[4],B2=qs[5],A3=qs[6],B3=qs[7];
        for (int j2 = 0; j2 < 60; j2 += 4) {
            rep_step(A0,B0,px2,py2,pz2,pn2,&s2); A0=qs[2*j2+ 8]; B0=qs[2*j2+ 9];
            rep_step(A1,B1,px2,py2,pz2,pn2,&s2); A1=qs[2*j2+10]; B1=qs[2*j2+11];
            rep_step(A2,B2,px2,py2,pz2,pn2,&s2); A2=qs[2*j2+12]; B2=qs[2*j2+13];
            rep_step(A3,B3,px2,py2,pz2,pn2,&s2); A3=qs[2*j2+14]; B3=qs[2*j2+15];
        }
        rep_step(A0,B0,px2,py2,pz2,pn2,&s2); rep_step(A1,B1,px2,py2,pz2,pn2,&s2);
        rep_step(A2,B2,px2,py2,pz2,pn2,&s2); rep_step(A3,B3,px2,py2,pz2,pn2,&s2);

        float bs = block_reduce_sum(s2.x + s2.y, red);
        if (tid == 0) atomicAdd(&ws[4], bs * has_contact[b]);
    }
}

// 80 blocks: reduce per-row mins; last block (ticket) finalizes into out[0].
//  [0,32): hand (dir x b)  [32,64): obj (dir x b)  [64,80): pen (b)
__global__ __launch_bounds__(256) void combine_kernel(
    const float* __restrict__ has_contact, float* __restrict__ ws,
    float* __restrict__ out)
{
    __shared__ float red[4];
    const unsigned* rowmin = (const unsigned*)(ws + WS_SCAL);
    int blk = blockIdx.x;
    int tid = threadIdx.x;

    int slot, rows, base, pen = 0;
    float w = 1.f;
    if (blk < 32) {
        int dir = blk >> 4, b = blk & 15;
        slot = dir; rows = 1024; base = dir*16384 + b*1024;
    } else if (blk < 64) {
        int idx = blk - 32; int dir = idx >> 4, b = idx & 15;
        slot = 2 + dir; rows = 2048; base = 32768 + dir*32768 + b*2048;
        w = has_contact[b];
    } else {
        int b = blk - 64;
        slot = 5; rows = 2048; base = 98304 + b*2048;
        w = has_contact[b]; pen = 1;
    }
    float s = 0.f;
    for (int n = tid; n < rows; n += 256) {
        float d = wsqrt(__uint_as_float(~rowmin[base + n]));
        s += pen ? fmaxf(MARGIN_PEN - d, 0.f) : d;
    }
    float bs = block_reduce_sum(s, red);
    if (tid == 0) {
        atomicAdd(&ws[slot], bs * w);
        __threadfence();
        unsigned* cnt = (unsigned*)(ws + 15);
        unsigned old = atomicAdd(cnt, 1u);
        if (old == 79u) {                       // last block finalizes
            __threadfence();
            float s0 = atomicAdd(&ws[0], 0.f), s1 = atomicAdd(&ws[1], 0.f);
            float s2 = atomicAdd(&ws[2], 0.f), s3 = atomicAdd(&ws[3], 0.f);
            float s4 = atomicAdd(&ws[4], 0.f), s5 = atomicAdd(&ws[5], 0.f);
            float s6 = atomicAdd(&ws[6], 0.f), s7 = atomicAdd(&ws[7], 0.f);
            float s8 = atomicAdd(&ws[8], 0.f), s9 = atomicAdd(&ws[9], 0.f);
            double vT    = s9;
            double valid = vT + 1e-6;
            double NOd   = (double)NO;
            // repulsion: sum relu(R-d) = hc-weighted (NO^2*R - S) minus diagonal
            double repw  = vT*NOd*NOd*(double)RADIUS_REP - (double)s4;
            double repx  = repw - vT*NOd*((double)RADIUS_REP - 1e-6);
            double loss_cd_hand = ((double)s0 + (double)s1) / (double)(B*NH);
            double loss_cd_obj  = ((double)s2 + (double)s3) / (NOd * valid);
            double loss_rep     = repx / (NOd * NOd * valid);
            double loss_pen     = (double)s5 / (NOd * valid);
            double loss_pose    = (double)s8 / valid;
            double loss_qpos    = (double)s7 / (double)(B*DQ);
            double loss_contact = (double)s6 / (double)(B*NH);
            double total = 5.0*loss_cd_hand + 5.0*loss_cd_obj + 2.0*loss_pose
                         + 1.0*loss_qpos + 2.0*loss_contact
                         + 0.5*loss_rep + 0.5*loss_pen;
            out[0] = (float)total;
        }
    }
}

extern "C" void kernel_launch(void* const* d_in, const int* in_sizes, int n_in,
                              void* d_out, int out_size, void* d_ws, size_t ws_size,
                              hipStream_t stream) {
    const float* pred_hand   = (const float*)d_in[0];
    const float* pred_obj    = (const float*)d_in[1];
    const float* pred_pose   = (const float*)d_in[2];
    const float* pred_qpos   = (const float*)d_in[3];
    const float* logits      = (const float*)d_in[4];
    const float* gt_hand     = (const float*)d_in[5];
    const float* gt_obj      = (const float*)d_in[6];
    const float* gt_pose     = (const float*)d_in[7];
    const float* gt_qpos     = (const float*)d_in[8];
    const float* gt_contact  = (const float*)d_in[9];
    const float* has_contact = (const float*)d_in[10];

    float* ws = (float*)d_ws;

    // single init: scalars+ticket <- 0, rowmin (complement-coded) <- 0
    hipMemsetAsync(ws, 0, (WS_SCAL + ROWS_TOTAL) * sizeof(float), stream);

    pairwise_kernel<<<2051, 256, 0, stream>>>(pred_hand, pred_obj, gt_hand, gt_obj,
                                              has_contact, logits, gt_contact,
                                              pred_qpos, gt_qpos, pred_pose, gt_pose, ws);
    combine_kernel<<<80, 256, 0, stream>>>(has_contact, ws, (float*)d_out);
}

// Round 7
// 57.708 us; speedup vs baseline: 4.2544x; 1.1681x over previous
//
#include <hip/hip_runtime.h>
#include <math.h>

// Problem constants (from reference setup_inputs)
#define B   16
#define NH  1024
#define NO  2048
#define DQ  24

#define ALPHA_FOCAL 0.25f
#define MARGIN_PEN  0.005f
#define RADIUS_REP  0.015f
#define R2REP       (RADIUS_REP * RADIUS_REP)

// ws layout:
//   float [0..16) scalar slots:
//     0,1: hand cd dir1/dir2   2,3: obj cd dir1/dir2 (weighted)
//     4: repulsion shifted sum S=sum min(d,R) incl diag (weighted)
//     5: penetration (weighted)  6: focal  7: qpos  8: pose (weighted)
//     9: valid   15: combine ticket counter (uint)
//   uint [16..16+131072): per-row ~bits(min d2) via atomicMax (init 0):
//     hand d1 [0,16384) hand d2 [16384,32768)
//     obj d1 [32768,65536) obj d2 [65536,98304) pen [98304,131072)
#define WS_SCAL    16
#define ROWS_TOTAL 131072

typedef float v2f __attribute__((ext_vector_type(2)));
typedef float v4f __attribute__((ext_vector_type(4)));

__device__ inline float wsqrt(float x) { return __builtin_amdgcn_sqrtf(x); }

__device__ inline float block_reduce_sum(float v, float* red) {
    #pragma unroll
    for (int off = 32; off > 0; off >>= 1) v += __shfl_down(v, off, 64);
    int lane = threadIdx.x & 63;
    int wid  = threadIdx.x >> 6;
    if (lane == 0) red[wid] = v;
    __syncthreads();
    float s = 0.f;
    if (threadIdx.x == 0) s = red[0] + red[1] + red[2] + red[3];
    __syncthreads();
    return s;   // valid in thread 0 only
}

// Work unit = one WAVE: 1024 P-rows (16/lane as 8 row-pairs) x 64 Q-cols.
// Per col: one uniform ds_read_b128 feeds 32 v_pk instructions.
// Wave ids (wave w of block blk-3 -> wid = (blk-3)*4 + w), 4096 total:
//  [   0,1024): repulsion     b(16) x pc(2) x jc(32)      (heavy: first)
//  [1024,3072): obj chamfer   dir(2) x b(16) x pc(2) x jc(32)
//  [3072,3584): hand chamfer  dir(2) x b(16) x jc(16)
//  [3584,4096): penetration   b(16) x pc(2) x jc(16)
// Blocks 0..2: focal / qpos / pose+valid.
__global__ __launch_bounds__(256, 3) void pairwise_kernel(
    const float* __restrict__ pred_hand, const float* __restrict__ pred_obj,
    const float* __restrict__ gt_hand,   const float* __restrict__ gt_obj,
    const float* __restrict__ has_contact,
    const float* __restrict__ logits,    const float* __restrict__ gt_contact,
    const float* __restrict__ pred_qpos, const float* __restrict__ gt_qpos,
    const float* __restrict__ pred_pose, const float* __restrict__ gt_pose,
    float* __restrict__ ws)
{
    __shared__ v4f  qs[256];    // 4 KiB: per wave a 64-col region {-2x,-2y,-2z,|q|^2}
    __shared__ float red[4];

    const int tid = threadIdx.x;
    const int blk = blockIdx.x;

    if (blk < 3) {              // small fused loss terms
        if (blk == 0) {
            float fsum = 0.f;
            for (int i = tid; i < B*NH; i += 256) {
                float l = logits[i];
                float y = gt_contact[i];
                float bce = fmaxf(l, 0.f) - l*y + log1pf(expf(-fabsf(l)));
                float pt  = expf(-bce);
                float om  = 1.f - pt;
                fsum += ALPHA_FOCAL * om * om * bce;
            }
            float fT = block_reduce_sum(fsum, red);
            if (tid == 0) atomicAdd(&ws[6], fT);
        } else if (blk == 1) {
            float qsum = 0.f;
            for (int i = tid; i < B*DQ; i += 256) {
                float d = pred_qpos[i] - gt_qpos[i];
                qsum += d*d;
            }
            float qT = block_reduce_sum(qsum, red);
            if (tid == 0) atomicAdd(&ws[7], qT);
        } else {
            float psum = 0.f, vsum = 0.f;
            if (tid < B) {
                const float* pp = pred_pose + tid*7;
                const float* gp = gt_pose   + tid*7;
                float lt = (fabsf(pp[0]-gp[0]) + fabsf(pp[1]-gp[1]) + fabsf(pp[2]-gp[2])) * (1.f/3.f);
                float npn = wsqrt(pp[3]*pp[3] + pp[4]*pp[4] + pp[5]*pp[5] + pp[6]*pp[6]);
                float ngn = wsqrt(gp[3]*gp[3] + gp[4]*gp[4] + gp[5]*gp[5] + gp[6]*gp[6]);
                float dot = (pp[3]*gp[3] + pp[4]*gp[4] + pp[5]*gp[5] + pp[6]*gp[6]) / (npn * ngn);
                float lr = 1.f - fabsf(dot);
                psum = (lt + 0.1f*lr) * has_contact[tid];
                vsum = has_contact[tid];
            }
            float pT = block_reduce_sum(psum, red);
            float vT = block_reduce_sum(vsum, red);
            if (tid == 0) { atomicAdd(&ws[8], pT); atomicAdd(&ws[9], vT); }
        }
        return;
    }

    const int w   = tid >> 6;
    const int l   = tid & 63;
    const int wid = ((blk - 3) << 2) | w;

    unsigned* rowmin = (unsigned*)(ws + WS_SCAL);
    const float* Pb; const float* Qb;
    int b, rowbase = 0, rep = 0;

    if (wid < 1024) {                       // repulsion
        b = wid >> 6; int pc = (wid >> 5) & 1, jc = wid & 31;
        Pb = pred_obj + b*NO*3 + pc*1024*3;
        Qb = pred_obj + b*NO*3 + jc*64*3;
        rep = 1;
    } else if (wid < 3072) {                // obj chamfer
        int t = wid - 1024;
        int dir = t >> 10, r = t & 1023;
        b = r >> 6; int pc = (r >> 5) & 1, jc = r & 31;
        Pb = (dir ? gt_obj : pred_obj) + b*NO*3 + pc*1024*3;
        Qb = (dir ? pred_obj : gt_obj) + b*NO*3 + jc*64*3;
        rowbase = 32768 + dir*32768 + b*2048 + pc*1024;
    } else if (wid < 3584) {                // hand chamfer
        int t = wid - 3072;
        int dir = t >> 8, r = t & 255;
        b = r >> 4; int jc = r & 15;
        Pb = (dir ? gt_hand : pred_hand) + b*NH*3;
        Qb = (dir ? pred_hand : gt_hand) + b*NH*3 + jc*64*3;
        rowbase = dir*16384 + b*1024;
    } else {                                // penetration
        int t = wid - 3584;
        b = t >> 5; int pc = (t >> 4) & 1, jc = t & 15;
        Pb = pred_obj  + b*NO*3 + pc*1024*3;
        Qb = pred_hand + b*NH*3 + jc*64*3;
        rowbase = 98304 + b*2048 + pc*1024;
    }

    // Stage this wave's 64 Q cols (one b128 write per lane, conflict-free)
    {
        const float* qp = Qb + l*3;
        float x = qp[0], y = qp[1], z = qp[2];
        qs[(w << 6) | l] = (v4f){-2.f*x, -2.f*y, -2.f*z, fmaf(x, x, fmaf(y, y, z*z))};
    }
    __syncthreads();

    // This lane's 16 P rows as 8 row-pairs (rows l+128k and l+128k+64)
    v2f px2[8], py2[8], pz2[8];
    #pragma unroll
    for (int kk = 0; kk < 8; ++kk) {
        const float* p0 = Pb + (l + (kk << 7)) * 3;
        const float* p1 = p0 + 192;
        px2[kk] = (v2f){p0[0], p1[0]};
        py2[kk] = (v2f){p0[1], p1[1]};
        pz2[kk] = (v2f){p0[2], p1[2]};
    }

    const v4f* qw = qs + (w << 6);

    if (rep) {
        v2f pn2[8];
        #pragma unroll
        for (int kk = 0; kk < 8; ++kk)
            pn2[kk] = __builtin_elementwise_fma(px2[kk], px2[kk],
                      __builtin_elementwise_fma(py2[kk], py2[kk], pz2[kk]*pz2[kk]));
        v2f sacc = (v2f){0.f, 0.f};
        const v2f vR = (v2f){RADIUS_REP, RADIUS_REP};
        auto rstep = [&](v4f Q) {
            v2f bx = __builtin_shufflevector(Q, Q, 0, 0);
            v2f by = __builtin_shufflevector(Q, Q, 1, 1);
            v2f bz = __builtin_shufflevector(Q, Q, 2, 2);
            v2f bw = __builtin_shufflevector(Q, Q, 3, 3);
            #pragma unroll
            for (int kk = 0; kk < 8; ++kk) {
                v2f t = __builtin_elementwise_fma(bz, pz2[kk], bw);
                t     = __builtin_elementwise_fma(by, py2[kk], t);
                t     = __builtin_elementwise_fma(bx, px2[kk], t);
                v2f d2 = t + pn2[kk];
                if (__any(fminf(d2.x, d2.y) < R2REP)) {
                    // accumulate min(d,R) exactly (diag d2~0 -> 1e-6, fixed later)
                    v2f dd;
                    dd.x = wsqrt(__builtin_amdgcn_fmed3f(d2.x, 1e-12f, R2REP));
                    dd.y = wsqrt(__builtin_amdgcn_fmed3f(d2.y, 1e-12f, R2REP));
                    sacc += dd;
                } else {
                    sacc += vR;     // min(d,R) = R for both elements
                }
            }
        };
        v4f Q0 = qw[0], Q1 = qw[1], Q2 = qw[2], Q3 = qw[3];
        for (int j = 0; j < 60; j += 4) {
            rstep(Q0); Q0 = qw[j+4];
            rstep(Q1); Q1 = qw[j+5];
            rstep(Q2); Q2 = qw[j+6];
            rstep(Q3); Q3 = qw[j+7];
        }
        rstep(Q0); rstep(Q1); rstep(Q2); rstep(Q3);

        float s = sacc.x + sacc.y;
        #pragma unroll
        for (int off = 32; off > 0; off >>= 1) s += __shfl_down(s, off, 64);
        if (l == 0) atomicAdd(&ws[4], s * has_contact[b]);
    } else {
        v2f m2[8];
        #pragma unroll
        for (int kk = 0; kk < 8; ++kk) m2[kk] = (v2f){1e30f, 1e30f};
        auto cstep = [&](v4f Q) {
            v2f bx = __builtin_shufflevector(Q, Q, 0, 0);
            v2f by = __builtin_shufflevector(Q, Q, 1, 1);
            v2f bz = __builtin_shufflevector(Q, Q, 2, 2);
            v2f bw = __builtin_shufflevector(Q, Q, 3, 3);
            #pragma unroll
            for (int kk = 0; kk < 8; ++kk) {
                v2f t = __builtin_elementwise_fma(bz, pz2[kk], bw);
                t     = __builtin_elementwise_fma(by, py2[kk], t);
                t     = __builtin_elementwise_fma(bx, px2[kk], t);
                m2[kk] = __builtin_elementwise_min(m2[kk], t);
            }
        };
        v4f Q0 = qw[0], Q1 = qw[1], Q2 = qw[2], Q3 = qw[3];
        for (int j = 0; j < 60; j += 4) {
            cstep(Q0); Q0 = qw[j+4];
            cstep(Q1); Q1 = qw[j+5];
            cstep(Q2); Q2 = qw[j+6];
            cstep(Q3); Q3 = qw[j+7];
        }
        cstep(Q0); cstep(Q1); cstep(Q2); cstep(Q3);

        #pragma unroll
        for (int kk = 0; kk < 8; ++kk) {
            #pragma unroll
            for (int e = 0; e < 2; ++e) {
                float x = px2[kk][e], y = py2[kk][e], z = pz2[kk][e];
                float pn = fmaf(x, x, fmaf(y, y, z*z));
                float mv = m2[kk][e] + pn;
                unsigned c = ~__float_as_uint(fmaxf(mv, 1e-12f));
                atomicMax(&rowmin[rowbase + l + (kk << 7) + (e << 6)], c);
            }
        }
    }
}

// 80 blocks: reduce per-row mins; last block (ticket) finalizes into out[0].
//  [0,32): hand (dir x b)  [32,64): obj (dir x b)  [64,80): pen (b)
__global__ __launch_bounds__(256) void combine_kernel(
    const float* __restrict__ has_contact, float* __restrict__ ws,
    float* __restrict__ out)
{
    __shared__ float red[4];
    const unsigned* rowmin = (const unsigned*)(ws + WS_SCAL);
    int blk = blockIdx.x;
    int tid = threadIdx.x;

    int slot, rows, base, pen = 0;
    float w = 1.f;
    if (blk < 32) {
        int dir = blk >> 4, b = blk & 15;
        slot = dir; rows = 1024; base = dir*16384 + b*1024;
    } else if (blk < 64) {
        int idx = blk - 32; int dir = idx >> 4, b = idx & 15;
        slot = 2 + dir; rows = 2048; base = 32768 + dir*32768 + b*2048;
        w = has_contact[b];
    } else {
        int b = blk - 64;
        slot = 5; rows = 2048; base = 98304 + b*2048;
        w = has_contact[b]; pen = 1;
    }
    float s = 0.f;
    for (int n = tid; n < rows; n += 256) {
        float d = wsqrt(__uint_as_float(~rowmin[base + n]));
        s += pen ? fmaxf(MARGIN_PEN - d, 0.f) : d;
    }
    float bs = block_reduce_sum(s, red);
    if (tid == 0) {
        atomicAdd(&ws[slot], bs * w);
        __threadfence();
        unsigned* cnt = (unsigned*)(ws + 15);
        unsigned old = atomicAdd(cnt, 1u);
        if (old == 79u) {                       // last block finalizes
            __threadfence();
            float s0 = atomicAdd(&ws[0], 0.f), s1 = atomicAdd(&ws[1], 0.f);
            float s2 = atomicAdd(&ws[2], 0.f), s3 = atomicAdd(&ws[3], 0.f);
            float s4 = atomicAdd(&ws[4], 0.f), s5 = atomicAdd(&ws[5], 0.f);
            float s6 = atomicAdd(&ws[6], 0.f), s7 = atomicAdd(&ws[7], 0.f);
            float s8 = atomicAdd(&ws[8], 0.f), s9 = atomicAdd(&ws[9], 0.f);
            double vT    = s9;
            double valid = vT + 1e-6;
            double NOd   = (double)NO;
            // repulsion: sum relu(R-d) = hc-weighted (NO^2*R - S) minus diagonal
            double repw  = vT*NOd*NOd*(double)RADIUS_REP - (double)s4;
            double repx  = repw - vT*NOd*((double)RADIUS_REP - 1e-6);
            double loss_cd_hand = ((double)s0 + (double)s1) / (double)(B*NH);
            double loss_cd_obj  = ((double)s2 + (double)s3) / (NOd * valid);
            double loss_rep     = repx / (NOd * NOd * valid);
            double loss_pen     = (double)s5 / (NOd * valid);
            double loss_pose    = (double)s8 / valid;
            double loss_qpos    = (double)s7 / (double)(B*DQ);
            double loss_contact = (double)s6 / (double)(B*NH);
            double total = 5.0*loss_cd_hand + 5.0*loss_cd_obj + 2.0*loss_pose
                         + 1.0*loss_qpos + 2.0*loss_contact
                         + 0.5*loss_rep + 0.5*loss_pen;
            out[0] = (float)total;
        }
    }
}

extern "C" void kernel_launch(void* const* d_in, const int* in_sizes, int n_in,
                              void* d_out, int out_size, void* d_ws, size_t ws_size,
                              hipStream_t stream) {
    const float* pred_hand   = (const float*)d_in[0];
    const float* pred_obj    = (const float*)d_in[1];
    const float* pred_pose   = (const float*)d_in[2];
    const float* pred_qpos   = (const float*)d_in[3];
    const float* logits      = (const float*)d_in[4];
    const float* gt_hand     = (const float*)d_in[5];
    const float* gt_obj      = (const float*)d_in[6];
    const float* gt_pose     = (const float*)d_in[7];
    const float* gt_qpos     = (const float*)d_in[8];
    const float* gt_contact  = (const float*)d_in[9];
    const float* has_contact = (const float*)d_in[10];

    float* ws = (float*)d_ws;

    // single init: scalars+ticket <- 0, rowmin (complement-coded) <- 0
    hipMemsetAsync(ws, 0, (WS_SCAL + ROWS_TOTAL) * sizeof(float), stream);

    pairwise_kernel<<<1027, 256, 0, stream>>>(pred_hand, pred_obj, gt_hand, gt_obj,
                                              has_contact, logits, gt_contact,
                                              pred_qpos, gt_qpos, pred_pose, gt_pose, ws);
    combine_kernel<<<80, 256, 0, stream>>>(has_contact, ws, (float*)d_out);
}